// Round 17
// baseline (356.952 us; speedup 1.0000x reference)
//
#include <hip/hip_runtime.h>
#include <hip/hip_bf16.h>
#include <cstdint>

#define D_MODEL 768
#define N_HEADS 12
#define D_HEAD  64
#define BATCH   2
#define SEQ     2048
#define NQ64    (SEQ / 64)          // 32 q64-blocks per bh
// (1/sqrt(64)) * log2(e): QK^T scores land directly in log2 domain (exp2 softmax)
#define SCALE_Q 0.18033688011112042f
#define NSL     4                   // kv slices per q64 block (= waves per block)
#define NBH     (BATCH * N_HEADS)   // 24

typedef float f32x4 __attribute__((ext_vector_type(4)));
typedef short s16x8 __attribute__((ext_vector_type(8)));
typedef short s16x4 __attribute__((ext_vector_type(4)));
typedef unsigned short u16;

static __device__ __forceinline__ u16 f2bf(float f) {
    union { float f; unsigned int u; } c; c.f = f;
    unsigned int u = c.u;
    u += 0x7fffu + ((u >> 16) & 1u);            // RNE
    return (u16)(u >> 16);
}
static __device__ __forceinline__ float b2f(u16 u) {
    union { unsigned u; float f; } c; c.u = ((unsigned)u) << 16; return c.f;
}
// fast 2^x: single v_exp_f32 via builtin (compiler-managed hazards; ~1 ULP).
static __device__ __forceinline__ float e2(float x) {
#if __has_builtin(__builtin_amdgcn_exp2f)
    return __builtin_amdgcn_exp2f(x);
#else
    return exp2f(x);
#endif
}
// hot-loop pack: 4 f32 -> 4 bf16 via the official packed-convert intrinsic
static __device__ __forceinline__ s16x4 pk4(float p0, float p1, float p2, float p3) {
    union { __hip_bfloat162 h[2]; s16x4 v; } u;
    u.h[0] = __float22bfloat162_rn(make_float2(p0, p1));
    u.h[1] = __float22bfloat162_rn(make_float2(p2, p3));
    return u.v;
}

static __device__ __forceinline__ f32x4 mfma16x32(s16x8 a, s16x8 b, f32x4 c) {
    return __builtin_amdgcn_mfma_f32_16x16x32_bf16(a, b, c, 0, 0, 0);
}
static __device__ __forceinline__ f32x4 mfma16x16(s16x4 a, s16x4 b, f32x4 c) {
#if __has_builtin(__builtin_amdgcn_mfma_f32_16x16x16bf16_1k)
    return __builtin_amdgcn_mfma_f32_16x16x16bf16_1k(a, b, c, 0, 0, 0);
#else
    asm volatile("v_mfma_f32_16x16x16_bf16 %0, %1, %2, %0" : "+v"(c) : "v"(a), "v"(b));
    return c;
#endif
}
// async global->LDS, 16B per lane; LDS dest must be linear in lane order.
static __device__ __forceinline__ void gload_lds16(const void* g, void* l) {
    __builtin_amdgcn_global_load_lds(
        (const __attribute__((address_space(1))) unsigned int*)g,
        (__attribute__((address_space(3))) unsigned int*)l, 16, 0, 0);
}

// ---------------------------------------------------------------------------
// fp32 -> bf16 convert for x, W_qkv, W_proj
// ---------------------------------------------------------------------------
__global__ __launch_bounds__(256)
void cvt3_kernel(const float* __restrict__ s0, u16* __restrict__ d0, int n0,
                 const float* __restrict__ s1, u16* __restrict__ d1, int n1,
                 const float* __restrict__ s2, u16* __restrict__ d2, int n2)
{
    const int idx4 = (blockIdx.x * 256 + threadIdx.x) * 4;
    const float* s; u16* d; int local;
    if (idx4 < n0)           { s = s0; d = d0; local = idx4; }
    else if (idx4 < n0 + n1) { s = s1; d = d1; local = idx4 - n0; }
    else if (idx4 < n0 + n1 + n2) { s = s2; d = d2; local = idx4 - n0 - n1; }
    else return;
    float4 v = *(const float4*)(s + local);
    ushort4 o;
    o.x = f2bf(v.x); o.y = f2bf(v.y); o.z = f2bf(v.z); o.w = f2bf(v.w);
    *(ushort4*)(d + local) = o;
}

// ---------------------------------------------------------------------------
// bf16 MFMA GEMM (NT): C[M,N] = A[M,K] @ B[N,K]^T + bias[N]   (unchanged, passing)
// ---------------------------------------------------------------------------
template<int BM, int BN, int MODE>
__global__ __launch_bounds__(256)
void mfma_gemm_kernel(const u16* __restrict__ A, const u16* __restrict__ Bw,
                      const float* __restrict__ bias,
                      float* __restrict__ outf,
                      u16* __restrict__ qo, u16* __restrict__ ko, u16* __restrict__ vt,
                      int M, int N, int K)
{
    constexpr int BK = 32;
    __shared__ u16 As[BM * BK];
    __shared__ u16 Bs[BN * BK];
    const int tid = threadIdx.x;
    const int wave = tid >> 6, lane = tid & 63;
    const int wr = wave >> 1, wc = wave & 1;
    constexpr int WM = BM / 2, WN = BN / 2, FI = WM / 16, FJ = WN / 16;
    const int g = lane >> 4, c = lane & 15;
    const int bm = blockIdx.x * BM, bn = blockIdx.y * BN;

    f32x4 acc[FI][FJ] = {};

    constexpr int IA = (BM * BK * 2) / (256 * 16);
    constexpr int IB = (BN * BK * 2) / (256 * 16);

    const u16* asrc[IA]; const u16* bsrc[IB];
    #pragma unroll
    for (int i = 0; i < IA; ++i) {
        const int idx = tid + i * 256;
        const int row = idx >> 2, kc = idx & 3;
        const int kcs = kc ^ ((row >> 1) & 3);
        asrc[i] = A + (size_t)(bm + row) * K + kcs * 8;
    }
    #pragma unroll
    for (int i = 0; i < IB; ++i) {
        const int idx = tid + i * 256;
        const int row = idx >> 2, kc = idx & 3;
        const int kcs = kc ^ ((row >> 1) & 3);
        bsrc[i] = Bw + (size_t)(bn + row) * K + kcs * 8;
    }
    const int gsw = g ^ ((c >> 1) & 3);

    for (int k0 = 0; k0 < K; k0 += BK) {
        if (k0) __syncthreads();
        #pragma unroll
        for (int i = 0; i < IA; ++i) gload_lds16(asrc[i] + k0, &As[(tid + i * 256) * 8]);
        #pragma unroll
        for (int i = 0; i < IB; ++i) gload_lds16(bsrc[i] + k0, &Bs[(tid + i * 256) * 8]);
        __syncthreads();

        s16x8 af[FI], bfr[FJ];
        #pragma unroll
        for (int i = 0; i < FI; ++i)
            af[i] = *(const s16x8*)&As[(wr * WM + i * 16 + c) * BK + gsw * 8];
        #pragma unroll
        for (int j = 0; j < FJ; ++j)
            bfr[j] = *(const s16x8*)&Bs[(wc * WN + j * 16 + c) * BK + gsw * 8];
        #pragma unroll
        for (int i = 0; i < FI; ++i)
            #pragma unroll
            for (int j = 0; j < FJ; ++j)
                acc[i][j] = mfma16x32(af[i], bfr[j], acc[i][j]);
    }

    if (MODE == 1) {
        #pragma unroll
        for (int j = 0; j < FJ; ++j) {
            const int col = bn + wc * WN + j * 16 + c;
            const float bv = bias[col];
            #pragma unroll
            for (int i = 0; i < FI; ++i) {
                const int row0 = bm + wr * WM + i * 16 + g * 4;
                #pragma unroll
                for (int r = 0; r < 4; ++r)
                    outf[(size_t)(row0 + r) * N + col] = acc[i][j][r] + bv;
            }
        }
    } else {
        const int which = bn / D_MODEL;
        #pragma unroll
        for (int j = 0; j < FJ; ++j) {
            const int gcol = bn + wc * WN + j * 16 + c;
            const float bv = bias[gcol];
            const int scol = gcol - which * D_MODEL;
            const int h = scol >> 6, d = scol & 63;
            if (which == 2) {
                #pragma unroll
                for (int i = 0; i < FI; ++i) {
                    const int row0 = bm + wr * WM + i * 16 + g * 4;
                    const int b = row0 >> 11, t = row0 & 2047;
                    ushort4 pv;
                    pv.x = f2bf(acc[i][j][0] + bv);
                    pv.y = f2bf(acc[i][j][1] + bv);
                    pv.z = f2bf(acc[i][j][2] + bv);
                    pv.w = f2bf(acc[i][j][3] + bv);
                    *(ushort4*)(vt + ((size_t)(b * N_HEADS + h) * 64 + d) * SEQ + t) = pv;
                }
            } else {
                u16* dst = (which == 0) ? qo : ko;
                const float sc = (which == 0) ? SCALE_Q : 1.0f;  // q in log2-domain units
                #pragma unroll
                for (int i = 0; i < FI; ++i) {
                    const int row0 = bm + wr * WM + i * 16 + g * 4;
                    const int b = row0 >> 11, t = row0 & 2047;
                    #pragma unroll
                    for (int r = 0; r < 4; ++r)
                        dst[(((size_t)(b * N_HEADS + h) * SEQ + t + r) << 6) + d] =
                            f2bf((acc[i][j][r] + bv) * sc);
                }
            }
        }
    }
}

// ---------------------------------------------------------------------------
// MFMA flash attention (r13 base: 64 q-rows/wave, 4-way in-block kv split,
// in-LDS combine, direct ao write, launch_bounds(256,3), no spills).
// Round-17 diffs ONLY (register-level; no geometry change; setprio dropped —
// r16 showed it slightly hurts this homogeneous-wave loop):
//  (a) DEPTH-3 K/V buffer rotation: 3 x 16-reg tile buffers, preload
//      t0..t0+2, unroll-by-3 {compute X(t); reload X(t+3)} -> each tile's
//      loads get ~2 iterations (~600cy) to land vs <1 before. Unified regs
//      ~164 <= 170 cap. Tripwire: WRITE_SIZE > 6144 = spills -> revert.
//  (b) chained QK mfma (C-in accumulate) -> saves the f32x4 add per TILEQ.
// ---------------------------------------------------------------------------
__global__ __launch_bounds__(256, 3)
void mfma_attn_kernel(const u16* __restrict__ qb, const u16* __restrict__ kb,
                      const u16* __restrict__ vtb, u16* __restrict__ ob)
{
    __shared__ __align__(16) u16 OL[NSL][64][64];     // 32 KB
    __shared__ float ML[NSL][2][64];                  // 2 KB
    const int tid = threadIdx.x;
    const int lane = tid & 63;
    const int s = tid >> 6;                          // kv-slice = wave id (0..3)
    const int blk = blockIdx.x;
    const int bh = blk % NBH;
    const int q = blk / NBH;                         // 0..31
    // round-robin-aware balance map (CU sums ~const; last 256 blocks lightest)
    const int jblk = (q <= 10) ? (q + 21) : (q <= 20) ? (31 - q) : (q - 21);

    const int nq = jblk + 1;                         // tiles per slice (exact)
    const int t0 = s * nq;
    const int t1 = t0 + nq;
    const int jq0 = 4 * jblk;                        // kv-tile index of q-subtile 0

    const int g = lane >> 4, c = lane & 15;
    const int rbase = g << 2;
    const int q0 = jblk << 6;

    // Q fragments for 4 subtiles
    s16x8 qa0[4], qa1[4];
    #pragma unroll
    for (int qq = 0; qq < 4; ++qq) {
        const u16* qp = qb + ((size_t)bh * SEQ + q0 + qq * 16 + c) * 64 + g * 8;
        qa0[qq] = *(const s16x8*)(qp);
        qa1[qq] = *(const s16x8*)(qp + 32);
    }

    f32x4 o[4][4] = {};
    float m[4] = {0.f, 0.f, 0.f, 0.f};
    float l[4] = {0.f, 0.f, 0.f, 0.f};

#define TILEQ(QQ, CK0, CK1, CV0, CV1, CV2, CV3, MASKED) {                         \
    f32x4 sv = {0,0,0,0};                                                         \
    sv = mfma16x32(CK0, qa0[QQ], sv);                                             \
    sv = mfma16x32(CK1, qa1[QQ], sv);      /* chained C-in accumulate */          \
    if (MASKED) {                                                                 \
        if (rbase + 0 > c) sv[0] = -1e30f;                                        \
        if (rbase + 1 > c) sv[1] = -1e30f;                                        \
        if (rbase + 2 > c) sv[2] = -1e30f;                                        \
        if (rbase + 3 > c) sv[3] = -1e30f;                                        \
    }                                                                             \
    float pmax = fmaxf(fmaxf(sv[0], sv[1]), fmaxf(sv[2], sv[3]));                 \
    if (__any(pmax > m[QQ] + 8.f)) {           /* rare: full rescale */           \
        pmax = fmaxf(pmax, __shfl_xor(pmax, 16));                                 \
        pmax = fmaxf(pmax, __shfl_xor(pmax, 32));                                 \
        const float mn = fmaxf(m[QQ], pmax);                                      \
        const float scr = e2(m[QQ] - mn);                                         \
        l[QQ] *= scr;                                                             \
        f32x4 scv;                                                                \
        scv[0] = __shfl(scr, rbase + 0);                                          \
        scv[1] = __shfl(scr, rbase + 1);                                          \
        scv[2] = __shfl(scr, rbase + 2);                                          \
        scv[3] = __shfl(scr, rbase + 3);                                          \
        o[QQ][0] *= scv; o[QQ][1] *= scv; o[QQ][2] *= scv; o[QQ][3] *= scv;       \
        m[QQ] = mn;                                                               \
    }                                                                             \
    const float p0 = e2(sv[0] - m[QQ]), p1 = e2(sv[1] - m[QQ]);                   \
    const float p2 = e2(sv[2] - m[QQ]), p3 = e2(sv[3] - m[QQ]);                   \
    l[QQ] += (p0 + p1) + (p2 + p3);                                               \
    const s16x4 pa = pk4(p0, p1, p2, p3);                                         \
    o[QQ][0] = mfma16x16(pa, CV0, o[QQ][0]);                                      \
    o[QQ][1] = mfma16x16(pa, CV1, o[QQ][1]);                                      \
    o[QQ][2] = mfma16x16(pa, CV2, o[QQ][2]);                                      \
    o[QQ][3] = mfma16x16(pa, CV3, o[QQ][3]);                                      \
}

#define TILE4(K0, K1, V0, V1, V2, V3, TT) {                                       \
    _Pragma("unroll")                                                             \
    for (int qq = 0; qq < 4; ++qq) {                                              \
        if ((TT) <= jq0 + qq) {                   /* wave-uniform causal skip */  \
            TILEQ(qq, K0, K1, V0, V1, V2, V3, ((TT) == jq0 + qq));                \
        }                                                                         \
    }                                                                             \
}

#define LOADKV(K0, K1, V0, V1, V2, V3) {                                          \
    K0 = *(const s16x8*)(kp);                                                     \
    K1 = *(const s16x8*)(kp + 32);                                                \
    V0 = *(const s16x4*)(vp);                                                     \
    V1 = *(const s16x4*)(vp + 16 * SEQ);                                          \
    V2 = *(const s16x4*)(vp + 32 * SEQ);                                          \
    V3 = *(const s16x4*)(vp + 48 * SEQ);                                          \
    kp += 1024; vp += 16;                                                         \
}

    {
        const u16* kp = kb + (size_t)bh * SEQ * 64 + c * 64 + g * 8 + (size_t)t0 * 1024;
        const u16* vp = vtb + ((size_t)bh * 64 + c) * SEQ + g * 4 + t0 * 16;

        s16x8 kA0, kA1, kB0, kB1, kC0, kC1;
        s16x4 vA0, vA1, vA2, vA3, vB0, vB1, vB2, vB3, vC0, vC1, vC2, vC3;
        // preload t0, t0+1, t0+2 (over-reads stay inside ws buffers; unused)
        LOADKV(kA0, kA1, vA0, vA1, vA2, vA3);
        LOADKV(kB0, kB1, vB0, vB1, vB2, vB3);
        LOADKV(kC0, kC1, vC0, vC1, vC2, vC3);

        int t = t0;
        for (; t + 3 <= t1; t += 3) {
            TILE4(kA0, kA1, vA0, vA1, vA2, vA3, t);
            LOADKV(kA0, kA1, vA0, vA1, vA2, vA3);      // tile t+3
            TILE4(kB0, kB1, vB0, vB1, vB2, vB3, t + 1);
            LOADKV(kB0, kB1, vB0, vB1, vB2, vB3);      // tile t+4
            TILE4(kC0, kC1, vC0, vC1, vC2, vC3, t + 2);
            LOADKV(kC0, kC1, vC0, vC1, vC2, vC3);      // tile t+5
        }
        if (t < t1)     { TILE4(kA0, kA1, vA0, vA1, vA2, vA3, t); }
        if (t + 1 < t1) { TILE4(kB0, kB1, vB0, vB1, vB2, vB3, t + 1); }
    }
#undef LOADKV
#undef TILE4
#undef TILEQ

    // ---- store partial to LDS (chunk-XOR swizzle: chunk' = chunk ^ (row&7)) --
    u16* OLs = &OL[s][0][0];
    #pragma unroll
    for (int qq = 0; qq < 4; ++qq) {
        float lt = l[qq] + __shfl_xor(l[qq], 16);
        lt += __shfl_xor(lt, 32);
        #pragma unroll
        for (int r = 0; r < 4; ++r) {
            const int row = qq * 16 + rbase + r;
            #pragma unroll
            for (int j = 0; j < 4; ++j) {
                const int col = c + 16 * j;
                const int idx = row * 64 + ((((col >> 3) ^ (row & 7)) << 3) | (col & 7));
                OLs[idx] = f2bf(o[qq][j][r]);
            }
        }
        if (g == 0) {
            ML[s][0][qq * 16 + c] = m[qq];
            ML[s][1][qq * 16 + c] = lt;
        }
    }
    __syncthreads();

    // ---- in-block combine: 256 threads, each does one (row, 16-col quarter) --
    {
        const int row = tid >> 2;                    // 0..63
        const int cq = (tid & 3) << 4;               // 0,16,32,48
        float mv[NSL], lv[NSL];
        float mm = -3.0e38f;
        #pragma unroll
        for (int sp = 0; sp < NSL; ++sp) {
            mv[sp] = ML[sp][0][row];
            lv[sp] = ML[sp][1][row];
            mm = fmaxf(mm, mv[sp]);
        }
        float w[NSL], denom = 0.f;
        #pragma unroll
        for (int sp = 0; sp < NSL; ++sp) {
            w[sp] = e2(mv[sp] - mm);                 // empty (row,slice): l=0 -> no-op
            denom += lv[sp] * w[sp];
        }
        const float inv = 1.0f / denom;              // diagonal slice always > 0

        float a[16] = {};
        #pragma unroll
        for (int sp = 0; sp < NSL; ++sp) {
            const float ws = w[sp] * inv;
            #pragma unroll
            for (int h2 = 0; h2 < 2; ++h2) {
                const int ch = (cq >> 3) + h2;
                const int idx = row * 64 + ((ch ^ (row & 7)) << 3);
                const uint4 xv = *(const uint4*)&OL[sp][0][idx];
                a[h2 * 8 + 0] += ws * b2f((u16)(xv.x & 0xffff));
                a[h2 * 8 + 1] += ws * b2f((u16)(xv.x >> 16));
                a[h2 * 8 + 2] += ws * b2f((u16)(xv.y & 0xffff));
                a[h2 * 8 + 3] += ws * b2f((u16)(xv.y >> 16));
                a[h2 * 8 + 4] += ws * b2f((u16)(xv.z & 0xffff));
                a[h2 * 8 + 5] += ws * b2f((u16)(xv.z >> 16));
                a[h2 * 8 + 6] += ws * b2f((u16)(xv.w & 0xffff));
                a[h2 * 8 + 7] += ws * b2f((u16)(xv.w >> 16));
            }
        }

        const int b = bh / N_HEADS, h = bh % N_HEADS;
        const int t = (jblk << 6) + row;
        u16* dst = ob + ((size_t)b * SEQ + t) * D_MODEL + h * 64 + cq;
        #pragma unroll
        for (int e4 = 0; e4 < 4; ++e4) {
            ushort4 ov;
            ov.x = f2bf(a[e4 * 4 + 0]);
            ov.y = f2bf(a[e4 * 4 + 1]);
            ov.z = f2bf(a[e4 * 4 + 2]);
            ov.w = f2bf(a[e4 * 4 + 3]);
            *(ushort4*)(dst + e4 * 4) = ov;
        }
    }
}

// ---------------------------------------------------------------------------
extern "C" void kernel_launch(void* const* d_in, const int* in_sizes, int n_in,
                              void* d_out, int out_size, void* d_ws, size_t ws_size,
                              hipStream_t stream)
{
    const float* x      = (const float*)d_in[0];
    // d_in[1] = mask: exactly triu(k=1) causal; applied analytically in-kernel.
    const float* W_qkv  = (const float*)d_in[2];
    const float* b_qkv  = (const float*)d_in[3];
    const float* W_proj = (const float*)d_in[4];
    const float* b_proj = (const float*)d_in[5];
    float* out = (float*)d_out;

    const int nX = BATCH * SEQ * D_MODEL;
    const int nWq = 3 * D_MODEL * D_MODEL;
    const int nWp = D_MODEL * D_MODEL;
    u16* xb  = (u16*)d_ws;
    u16* wqb = xb + nX;
    u16* wpb = wqb + nWq;
    u16* qbf = wpb + nWp;
    u16* kbf = qbf + nX;
    u16* vtb = kbf + nX;
    u16* ao  = vtb + nX;                 // bf16 [B,T,C]

    const int tot4 = (nX + nWq + nWp) / 4;
    cvt3_kernel<<<(tot4 + 255) / 256, 256, 0, stream>>>(x, xb, nX, W_qkv, wqb, nWq,
                                                        W_proj, wpb, nWp);

    mfma_gemm_kernel<128, 128, 0><<<dim3(32, 18), 256, 0, stream>>>(
        xb, wqb, b_qkv, nullptr, qbf, kbf, vtb, BATCH * SEQ, 3 * D_MODEL, D_MODEL);

    // 64 q-rows/wave, 4-way in-block split-K, 3 blocks/CU co-resident
    mfma_attn_kernel<<<dim3(NQ64 * NBH), 256, 0, stream>>>(
        qbf, kbf, vtb, ao);

    mfma_gemm_kernel<128, 64, 1><<<dim3(32, 12), 256, 0, stream>>>(
        ao, wpb, b_proj, out, nullptr, nullptr, nullptr, BATCH * SEQ, D_MODEL, D_MODEL);
}

// Round 18
// 124.885 us; speedup vs baseline: 2.8583x; 2.8583x over previous
//
#include <hip/hip_runtime.h>
#include <hip/hip_bf16.h>
#include <cstdint>

#define D_MODEL 768
#define N_HEADS 12
#define D_HEAD  64
#define BATCH   2
#define SEQ     2048
#define NQ64    (SEQ / 64)          // 32 q64-blocks per bh
// (1/sqrt(64)) * log2(e): QK^T scores land directly in log2 domain (exp2 softmax)
#define SCALE_Q 0.18033688011112042f
#define NSL     4                   // kv slices per q64 window (= waves per block)
#define NBH     (BATCH * N_HEADS)   // 24

typedef float f32x4 __attribute__((ext_vector_type(4)));
typedef short s16x8 __attribute__((ext_vector_type(8)));
typedef short s16x4 __attribute__((ext_vector_type(4)));
typedef unsigned short u16;

static __device__ __forceinline__ u16 f2bf(float f) {
    union { float f; unsigned int u; } c; c.f = f;
    unsigned int u = c.u;
    u += 0x7fffu + ((u >> 16) & 1u);            // RNE
    return (u16)(u >> 16);
}
static __device__ __forceinline__ float b2f(u16 u) {
    union { unsigned u; float f; } c; c.u = ((unsigned)u) << 16; return c.f;
}
// fast 2^x: single v_exp_f32 via builtin (compiler-managed hazards; ~1 ULP).
static __device__ __forceinline__ float e2(float x) {
#if __has_builtin(__builtin_amdgcn_exp2f)
    return __builtin_amdgcn_exp2f(x);
#else
    return exp2f(x);
#endif
}
// hot-loop pack: 4 f32 -> 4 bf16 via the official packed-convert intrinsic
static __device__ __forceinline__ s16x4 pk4(float p0, float p1, float p2, float p3) {
    union { __hip_bfloat162 h[2]; s16x4 v; } u;
    u.h[0] = __float22bfloat162_rn(make_float2(p0, p1));
    u.h[1] = __float22bfloat162_rn(make_float2(p2, p3));
    return u.v;
}

static __device__ __forceinline__ f32x4 mfma16x32(s16x8 a, s16x8 b, f32x4 c) {
    return __builtin_amdgcn_mfma_f32_16x16x32_bf16(a, b, c, 0, 0, 0);
}
static __device__ __forceinline__ f32x4 mfma16x16(s16x4 a, s16x4 b, f32x4 c) {
#if __has_builtin(__builtin_amdgcn_mfma_f32_16x16x16bf16_1k)
    return __builtin_amdgcn_mfma_f32_16x16x16bf16_1k(a, b, c, 0, 0, 0);
#else
    asm volatile("v_mfma_f32_16x16x16_bf16 %0, %1, %2, %0" : "+v"(c) : "v"(a), "v"(b));
    return c;
#endif
}
// async global->LDS, 16B per lane; LDS dest must be linear in lane order.
static __device__ __forceinline__ void gload_lds16(const void* g, void* l) {
    __builtin_amdgcn_global_load_lds(
        (const __attribute__((address_space(1))) unsigned int*)g,
        (__attribute__((address_space(3))) unsigned int*)l, 16, 0, 0);
}

// ---------------------------------------------------------------------------
// fp32 -> bf16 convert for x, W_qkv, W_proj
// ---------------------------------------------------------------------------
__global__ __launch_bounds__(256)
void cvt3_kernel(const float* __restrict__ s0, u16* __restrict__ d0, int n0,
                 const float* __restrict__ s1, u16* __restrict__ d1, int n1,
                 const float* __restrict__ s2, u16* __restrict__ d2, int n2)
{
    const int idx4 = (blockIdx.x * 256 + threadIdx.x) * 4;
    const float* s; u16* d; int local;
    if (idx4 < n0)           { s = s0; d = d0; local = idx4; }
    else if (idx4 < n0 + n1) { s = s1; d = d1; local = idx4 - n0; }
    else if (idx4 < n0 + n1 + n2) { s = s2; d = d2; local = idx4 - n0 - n1; }
    else return;
    float4 v = *(const float4*)(s + local);
    ushort4 o;
    o.x = f2bf(v.x); o.y = f2bf(v.y); o.z = f2bf(v.z); o.w = f2bf(v.w);
    *(ushort4*)(d + local) = o;
}

// ---------------------------------------------------------------------------
// bf16 MFMA GEMM (NT): C[M,N] = A[M,K] @ B[N,K]^T + bias[N]   (unchanged, passing)
// ---------------------------------------------------------------------------
template<int BM, int BN, int MODE>
__global__ __launch_bounds__(256)
void mfma_gemm_kernel(const u16* __restrict__ A, const u16* __restrict__ Bw,
                      const float* __restrict__ bias,
                      float* __restrict__ outf,
                      u16* __restrict__ qo, u16* __restrict__ ko, u16* __restrict__ vt,
                      int M, int N, int K)
{
    constexpr int BK = 32;
    __shared__ u16 As[BM * BK];
    __shared__ u16 Bs[BN * BK];
    const int tid = threadIdx.x;
    const int wave = tid >> 6, lane = tid & 63;
    const int wr = wave >> 1, wc = wave & 1;
    constexpr int WM = BM / 2, WN = BN / 2, FI = WM / 16, FJ = WN / 16;
    const int g = lane >> 4, c = lane & 15;
    const int bm = blockIdx.x * BM, bn = blockIdx.y * BN;

    f32x4 acc[FI][FJ] = {};

    constexpr int IA = (BM * BK * 2) / (256 * 16);
    constexpr int IB = (BN * BK * 2) / (256 * 16);

    const u16* asrc[IA]; const u16* bsrc[IB];
    #pragma unroll
    for (int i = 0; i < IA; ++i) {
        const int idx = tid + i * 256;
        const int row = idx >> 2, kc = idx & 3;
        const int kcs = kc ^ ((row >> 1) & 3);
        asrc[i] = A + (size_t)(bm + row) * K + kcs * 8;
    }
    #pragma unroll
    for (int i = 0; i < IB; ++i) {
        const int idx = tid + i * 256;
        const int row = idx >> 2, kc = idx & 3;
        const int kcs = kc ^ ((row >> 1) & 3);
        bsrc[i] = Bw + (size_t)(bn + row) * K + kcs * 8;
    }
    const int gsw = g ^ ((c >> 1) & 3);

    for (int k0 = 0; k0 < K; k0 += BK) {
        if (k0) __syncthreads();
        #pragma unroll
        for (int i = 0; i < IA; ++i) gload_lds16(asrc[i] + k0, &As[(tid + i * 256) * 8]);
        #pragma unroll
        for (int i = 0; i < IB; ++i) gload_lds16(bsrc[i] + k0, &Bs[(tid + i * 256) * 8]);
        __syncthreads();

        s16x8 af[FI], bfr[FJ];
        #pragma unroll
        for (int i = 0; i < FI; ++i)
            af[i] = *(const s16x8*)&As[(wr * WM + i * 16 + c) * BK + gsw * 8];
        #pragma unroll
        for (int j = 0; j < FJ; ++j)
            bfr[j] = *(const s16x8*)&Bs[(wc * WN + j * 16 + c) * BK + gsw * 8];
        #pragma unroll
        for (int i = 0; i < FI; ++i)
            #pragma unroll
            for (int j = 0; j < FJ; ++j)
                acc[i][j] = mfma16x32(af[i], bfr[j], acc[i][j]);
    }

    if (MODE == 1) {
        #pragma unroll
        for (int j = 0; j < FJ; ++j) {
            const int col = bn + wc * WN + j * 16 + c;
            const float bv = bias[col];
            #pragma unroll
            for (int i = 0; i < FI; ++i) {
                const int row0 = bm + wr * WM + i * 16 + g * 4;
                #pragma unroll
                for (int r = 0; r < 4; ++r)
                    outf[(size_t)(row0 + r) * N + col] = acc[i][j][r] + bv;
            }
        }
    } else {
        const int which = bn / D_MODEL;
        #pragma unroll
        for (int j = 0; j < FJ; ++j) {
            const int gcol = bn + wc * WN + j * 16 + c;
            const float bv = bias[gcol];
            const int scol = gcol - which * D_MODEL;
            const int h = scol >> 6, d = scol & 63;
            if (which == 2) {
                #pragma unroll
                for (int i = 0; i < FI; ++i) {
                    const int row0 = bm + wr * WM + i * 16 + g * 4;
                    const int b = row0 >> 11, t = row0 & 2047;
                    ushort4 pv;
                    pv.x = f2bf(acc[i][j][0] + bv);
                    pv.y = f2bf(acc[i][j][1] + bv);
                    pv.z = f2bf(acc[i][j][2] + bv);
                    pv.w = f2bf(acc[i][j][3] + bv);
                    *(ushort4*)(vt + ((size_t)(b * N_HEADS + h) * 64 + d) * SEQ + t) = pv;
                }
            } else {
                u16* dst = (which == 0) ? qo : ko;
                const float sc = (which == 0) ? SCALE_Q : 1.0f;  // q in log2-domain units
                #pragma unroll
                for (int i = 0; i < FI; ++i) {
                    const int row0 = bm + wr * WM + i * 16 + g * 4;
                    const int b = row0 >> 11, t = row0 & 2047;
                    #pragma unroll
                    for (int r = 0; r < 4; ++r)
                        dst[(((size_t)(b * N_HEADS + h) * SEQ + t + r) << 6) + d] =
                            f2bf((acc[i][j][r] + bv) * sc);
                }
            }
        }
    }
}

// ---------------------------------------------------------------------------
// Pair-phase attention, v2. One phase = EXACT r13 kernel body (kv loop with
// depth-1 prefetch ring + in-LDS 4-slice combine), emitting an UNNORMALIZED
// partial {O~, m, l} for (bh, jblk, half). The __noinline__ boundary is the
// spill fix: r15's inlined 2-phase mega-body merged live ranges past the
// 170-reg cap of launch_bounds(256,3) and spilled (77MB WRITE); the callee
// here has r13's proven ~148-reg footprint and the two calls share nothing
// but SGPR args. Function-scope __shared__ -> both calls reuse one LDS
// buffer (entry barrier orders reuse). Per wave: ceil half-windows of q64 p
// and q64 31-p sum to 16-17 iters, UNIFORM over all 3072 waves; grid = 768 =
// exactly co-resident (3 blocks/CU). Tripwire: attn WRITE_SIZE >> 20 MB =
// spills -> revert to r13.
// ---------------------------------------------------------------------------
__device__ __attribute__((noinline)) void attn_phase(
    int jblk, int h, int bh, int tid,
    const u16* __restrict__ qb, const u16* __restrict__ kb,
    const u16* __restrict__ vtb,
    u16* __restrict__ pO, float* __restrict__ pML)
{
    __shared__ __align__(16) u16 OL[NSL][64][64];     // 32 KB (shared by both calls)
    __shared__ float ML[NSL][2][64];                  // 2 KB
    const int lane = tid & 63;
    const int s = tid >> 6;                          // kv-slice = wave id (0..3)
    const int g = lane >> 4, c = lane & 15;
    const int rbase = g << 2;

    const int ntt = 4 * (jblk + 1);                  // q64's total kv 16-tiles
    const int hl = ntt >> 1;                         // half-window length
    const int w0 = h * hl;
    const int t0 = w0 + (hl * s) / 4;
    const int t1 = w0 + (hl * (s + 1)) / 4;          // may equal t0 (small jblk)
    const int jq0 = 4 * jblk;
    const int q0 = jblk << 6;

    // Q fragments for 4 subtiles
    s16x8 qa0[4], qa1[4];
    #pragma unroll
    for (int qq = 0; qq < 4; ++qq) {
        const u16* qp = qb + ((size_t)bh * SEQ + q0 + qq * 16 + c) * 64 + g * 8;
        qa0[qq] = *(const s16x8*)(qp);
        qa1[qq] = *(const s16x8*)(qp + 32);
    }

    f32x4 o[4][4] = {};
    float m[4] = {0.f, 0.f, 0.f, 0.f};
    float l[4] = {0.f, 0.f, 0.f, 0.f};

#define TILEQ(QQ, CK0, CK1, CV0, CV1, CV2, CV3, MASKED) {                         \
    f32x4 sa = {0,0,0,0}, sb = {0,0,0,0};                                         \
    sa = mfma16x32(CK0, qa0[QQ], sa);                                             \
    sb = mfma16x32(CK1, qa1[QQ], sb);                                             \
    f32x4 sv = sa + sb;                                                           \
    if (MASKED) {                                                                 \
        if (rbase + 0 > c) sv[0] = -1e30f;                                        \
        if (rbase + 1 > c) sv[1] = -1e30f;                                        \
        if (rbase + 2 > c) sv[2] = -1e30f;                                        \
        if (rbase + 3 > c) sv[3] = -1e30f;                                        \
    }                                                                             \
    float pmax = fmaxf(fmaxf(sv[0], sv[1]), fmaxf(sv[2], sv[3]));                 \
    if (__any(pmax > m[QQ] + 8.f)) {           /* rare: full rescale */           \
        pmax = fmaxf(pmax, __shfl_xor(pmax, 16));                                 \
        pmax = fmaxf(pmax, __shfl_xor(pmax, 32));                                 \
        const float mn = fmaxf(m[QQ], pmax);                                      \
        const float scr = e2(m[QQ] - mn);                                         \
        l[QQ] *= scr;                                                             \
        f32x4 scv;                                                                \
        scv[0] = __shfl(scr, rbase + 0);                                          \
        scv[1] = __shfl(scr, rbase + 1);                                          \
        scv[2] = __shfl(scr, rbase + 2);                                          \
        scv[3] = __shfl(scr, rbase + 3);                                          \
        o[QQ][0] *= scv; o[QQ][1] *= scv; o[QQ][2] *= scv; o[QQ][3] *= scv;       \
        m[QQ] = mn;                                                               \
    }                                                                             \
    const float p0 = e2(sv[0] - m[QQ]), p1 = e2(sv[1] - m[QQ]);                   \
    const float p2 = e2(sv[2] - m[QQ]), p3 = e2(sv[3] - m[QQ]);                   \
    l[QQ] += (p0 + p1) + (p2 + p3);                                               \
    const s16x4 pa = pk4(p0, p1, p2, p3);                                         \
    o[QQ][0] = mfma16x16(pa, CV0, o[QQ][0]);                                      \
    o[QQ][1] = mfma16x16(pa, CV1, o[QQ][1]);                                      \
    o[QQ][2] = mfma16x16(pa, CV2, o[QQ][2]);                                      \
    o[QQ][3] = mfma16x16(pa, CV3, o[QQ][3]);                                      \
}

    if (t0 < t1) {
        const u16* kp = kb + (size_t)bh * SEQ * 64 + c * 64 + g * 8 + (size_t)t0 * 1024;
        const u16* vp = vtb + ((size_t)bh * 64 + c) * SEQ + g * 4 + t0 * 16;

        // preload tile t0 (depth-1 ring, r13-proven)
        s16x8 ck0 = *(const s16x8*)(kp);
        s16x8 ck1 = *(const s16x8*)(kp + 32);
        s16x4 cv0 = *(const s16x4*)(vp);
        s16x4 cv1 = *(const s16x4*)(vp + 16 * SEQ);
        s16x4 cv2 = *(const s16x4*)(vp + 32 * SEQ);
        s16x4 cv3 = *(const s16x4*)(vp + 48 * SEQ);

        for (int t = t0; t < t1; ++t) {
            kp += 1024; vp += 16;
            const s16x8 nk0 = *(const s16x8*)(kp);
            const s16x8 nk1 = *(const s16x8*)(kp + 32);
            const s16x4 nv0 = *(const s16x4*)(vp);
            const s16x4 nv1 = *(const s16x4*)(vp + 16 * SEQ);
            const s16x4 nv2 = *(const s16x4*)(vp + 32 * SEQ);
            const s16x4 nv3 = *(const s16x4*)(vp + 48 * SEQ);

            #pragma unroll
            for (int qq = 0; qq < 4; ++qq) {
                if (t <= jq0 + qq) {                 // wave-uniform causal skip
                    TILEQ(qq, ck0, ck1, cv0, cv1, cv2, cv3, (t == jq0 + qq));
                }
            }
            ck0 = nk0; ck1 = nk1;
            cv0 = nv0; cv1 = nv1; cv2 = nv2; cv3 = nv3;
        }
    }
#undef TILEQ

    // ---- store partial to LDS (barrier first: prior call's combine reads) ----
    __syncthreads();
    u16* OLs = &OL[s][0][0];
    #pragma unroll
    for (int qq = 0; qq < 4; ++qq) {
        float lt = l[qq] + __shfl_xor(l[qq], 16);
        lt += __shfl_xor(lt, 32);
        #pragma unroll
        for (int r = 0; r < 4; ++r) {
            const int row = qq * 16 + rbase + r;
            #pragma unroll
            for (int j = 0; j < 4; ++j) {
                const int col = c + 16 * j;
                const int idx = row * 64 + ((((col >> 3) ^ (row & 7)) << 3) | (col & 7));
                OLs[idx] = f2bf(o[qq][j][r]);
            }
        }
        if (g == 0) {
            ML[s][0][qq * 16 + c] = m[qq];
            ML[s][1][qq * 16 + c] = lt;
        }
    }
    __syncthreads();

    // ---- in-block combine -> unnormalized partial {O~, m, l} -----------------
    {
        const int row = tid >> 2;                    // 0..63
        const int cq = (tid & 3) << 4;               // 0,16,32,48
        float mv[NSL], lv[NSL];
        float mm = -3.0e38f;
        #pragma unroll
        for (int sp = 0; sp < NSL; ++sp) {
            mv[sp] = ML[sp][0][row];
            lv[sp] = ML[sp][1][row];
            mm = fmaxf(mm, mv[sp]);
        }
        float w[NSL], denom = 0.f;
        #pragma unroll
        for (int sp = 0; sp < NSL; ++sp) {
            w[sp] = e2(mv[sp] - mm);                 // empty slice: l=0 -> no-op
            denom += lv[sp] * w[sp];
        }

        float a[16] = {};
        #pragma unroll
        for (int sp = 0; sp < NSL; ++sp) {
            const float ws = w[sp];                  // unnormalized accumulate
            #pragma unroll
            for (int h2 = 0; h2 < 2; ++h2) {
                const int ch = (cq >> 3) + h2;
                const int idx = row * 64 + ((ch ^ (row & 7)) << 3);
                const uint4 xv = *(const uint4*)&OL[sp][0][idx];
                a[h2 * 8 + 0] += ws * b2f((u16)(xv.x & 0xffff));
                a[h2 * 8 + 1] += ws * b2f((u16)(xv.x >> 16));
                a[h2 * 8 + 2] += ws * b2f((u16)(xv.y & 0xffff));
                a[h2 * 8 + 3] += ws * b2f((u16)(xv.y >> 16));
                a[h2 * 8 + 4] += ws * b2f((u16)(xv.z & 0xffff));
                a[h2 * 8 + 5] += ws * b2f((u16)(xv.z >> 16));
                a[h2 * 8 + 6] += ws * b2f((u16)(xv.w & 0xffff));
                a[h2 * 8 + 7] += ws * b2f((u16)(xv.w >> 16));
            }
        }

        const int ps = (bh * NQ64 + jblk) * 2 + h;
        u16* Od = pO + (size_t)ps * 4096 + row * 64 + cq;
        #pragma unroll
        for (int e4 = 0; e4 < 4; ++e4) {
            ushort4 ov;
            ov.x = f2bf(a[e4 * 4 + 0]);
            ov.y = f2bf(a[e4 * 4 + 1]);
            ov.z = f2bf(a[e4 * 4 + 2]);
            ov.w = f2bf(a[e4 * 4 + 3]);
            *(ushort4*)(Od + e4 * 4) = ov;
        }
        if ((tid & 3) == 0) {
            pML[(size_t)ps * 128 + row]      = mm;
            pML[(size_t)ps * 128 + 64 + row] = denom;
        }
    }
}

__global__ __launch_bounds__(256, 3)
void mfma_attn_kernel(const u16* __restrict__ qb, const u16* __restrict__ kb,
                      const u16* __restrict__ vtb,
                      u16* __restrict__ pO, float* __restrict__ pML)
{
    const int tid = threadIdx.x;
    const int blk = blockIdx.x;
    const int bh = blk % NBH;
    const int u = blk / NBH;                         // 0..31
    const int p = u >> 1, h = u & 1;                 // pair index, half index
    attn_phase(p,      h, bh, tid, qb, kb, vtb, pO, pML);   // light q64
    attn_phase(31 - p, h, bh, tid, qb, kb, vtb, pO, pML);   // heavy q64
}

// ---------------------------------------------------------------------------
// Merge the two kv-half partials of every q64 into ao [B,T,C] bf16.
// 768 blocks (bh x 32 q64s), 256 thr: row = tid>>2, 16 cols each.
// Every q-row has its diagonal element in one of the halves -> denom > 0.
// ---------------------------------------------------------------------------
__global__ __launch_bounds__(256)
void attn_merge_kernel(const u16* __restrict__ pO, const float* __restrict__ pML,
                       u16* __restrict__ ob)
{
    const int blk = blockIdx.x;
    const int bh = blk % NBH;
    const int j = blk / NBH;                         // q64 index 0..31
    const int tid = threadIdx.x;
    const int row = tid >> 2;
    const int cq = (tid & 3) << 4;
    const int ps = (bh * NQ64 + j) * 2;

    const float m0 = pML[(size_t)ps * 128 + row];
    const float l0 = pML[(size_t)ps * 128 + 64 + row];
    const float m1 = pML[(size_t)(ps + 1) * 128 + row];
    const float l1 = pML[(size_t)(ps + 1) * 128 + 64 + row];
    const float mm = fmaxf(m0, m1);
    const float w0 = e2(m0 - mm), w1 = e2(m1 - mm);
    const float inv = 1.0f / (l0 * w0 + l1 * w1);
    const float a0 = w0 * inv, a1 = w1 * inv;

    const u16* O0 = pO + (size_t)ps * 4096 + row * 64 + cq;
    const u16* O1 = O0 + 4096;
    const int b = bh / N_HEADS, h = bh % N_HEADS;
    const int t = (j << 6) + row;
    u16* dst = ob + ((size_t)b * SEQ + t) * D_MODEL + h * 64 + cq;
    #pragma unroll
    for (int e4 = 0; e4 < 4; ++e4) {
        const ushort4 x0 = *(const ushort4*)(O0 + e4 * 4);
        const ushort4 x1 = *(const ushort4*)(O1 + e4 * 4);
        ushort4 ov;
        ov.x = f2bf(a0 * b2f(x0.x) + a1 * b2f(x1.x));
        ov.y = f2bf(a0 * b2f(x0.y) + a1 * b2f(x1.y));
        ov.z = f2bf(a0 * b2f(x0.z) + a1 * b2f(x1.z));
        ov.w = f2bf(a0 * b2f(x0.w) + a1 * b2f(x1.w));
        *(ushort4*)(dst + e4 * 4) = ov;
    }
}

// ---------------------------------------------------------------------------
extern "C" void kernel_launch(void* const* d_in, const int* in_sizes, int n_in,
                              void* d_out, int out_size, void* d_ws, size_t ws_size,
                              hipStream_t stream)
{
    const float* x      = (const float*)d_in[0];
    // d_in[1] = mask: exactly triu(k=1) causal; applied analytically in-kernel.
    const float* W_qkv  = (const float*)d_in[2];
    const float* b_qkv  = (const float*)d_in[3];
    const float* W_proj = (const float*)d_in[4];
    const float* b_proj = (const float*)d_in[5];
    float* out = (float*)d_out;

    const int nX = BATCH * SEQ * D_MODEL;
    const int nWq = 3 * D_MODEL * D_MODEL;
    const int nWp = D_MODEL * D_MODEL;
    u16* xb  = (u16*)d_ws;
    u16* wqb = xb + nX;
    u16* wpb = wqb + nWq;
    u16* qbf = wpb + nWp;
    u16* kbf = qbf + nX;
    u16* vtb = kbf + nX;
    u16* ao  = vtb + nX;                 // bf16 [B,T,C]
    u16* pO  = ao + nX;                  // partials O~: 1536 x 4096 u16 (12.6 MB)
    float* pML = (float*)(pO + (size_t)NBH * NQ64 * 2 * 4096);  // 1536 x 128 f32

    const int tot4 = (nX + nWq + nWp) / 4;
    cvt3_kernel<<<(tot4 + 255) / 256, 256, 0, stream>>>(x, xb, nX, W_qkv, wqb, nWq,
                                                        W_proj, wpb, nWp);

    mfma_gemm_kernel<128, 128, 0><<<dim3(32, 18), 256, 0, stream>>>(
        xb, wqb, b_qkv, nullptr, qbf, kbf, vtb, BATCH * SEQ, 3 * D_MODEL, D_MODEL);

    // pair-phase attention: 768 uniform blocks -> partials, then 2-way merge
    mfma_attn_kernel<<<dim3(NQ64 * NBH), 256, 0, stream>>>(
        qbf, kbf, vtb, pO, pML);
    attn_merge_kernel<<<dim3(NQ64 * NBH), 256, 0, stream>>>(pO, pML, ao);

    mfma_gemm_kernel<128, 64, 1><<<dim3(32, 12), 256, 0, stream>>>(
        ao, wpb, b_proj, out, nullptr, nullptr, nullptr, BATCH * SEQ, D_MODEL, D_MODEL);
}

// Round 19
// 96.482 us; speedup vs baseline: 3.6997x; 1.2944x over previous
//
#include <hip/hip_runtime.h>
#include <hip/hip_bf16.h>
#include <cstdint>

#define D_MODEL 768
#define N_HEADS 12
#define D_HEAD  64
#define BATCH   2
#define SEQ     2048
#define NQ64    (SEQ / 64)          // 32 q64-blocks per bh
// (1/sqrt(64)) * log2(e): QK^T scores land directly in log2 domain (exp2 softmax)
#define SCALE_Q 0.18033688011112042f
#define NSL     4                   // kv slices per q64 block (= waves per block)
#define NBH     (BATCH * N_HEADS)   // 24

typedef float f32x4 __attribute__((ext_vector_type(4)));
typedef short s16x8 __attribute__((ext_vector_type(8)));
typedef short s16x4 __attribute__((ext_vector_type(4)));
typedef unsigned short u16;

static __device__ __forceinline__ u16 f2bf(float f) {
    union { float f; unsigned int u; } c; c.f = f;
    unsigned int u = c.u;
    u += 0x7fffu + ((u >> 16) & 1u);            // RNE
    return (u16)(u >> 16);
}
static __device__ __forceinline__ float b2f(u16 u) {
    union { unsigned u; float f; } c; c.u = ((unsigned)u) << 16; return c.f;
}
// fast 2^x: single v_exp_f32 via builtin (compiler-managed hazards; ~1 ULP).
static __device__ __forceinline__ float e2(float x) {
#if __has_builtin(__builtin_amdgcn_exp2f)
    return __builtin_amdgcn_exp2f(x);
#else
    return exp2f(x);
#endif
}
// hot-loop pack: 4 f32 -> 4 bf16 via the official packed-convert intrinsic
static __device__ __forceinline__ s16x4 pk4(float p0, float p1, float p2, float p3) {
    union { __hip_bfloat162 h[2]; s16x4 v; } u;
    u.h[0] = __float22bfloat162_rn(make_float2(p0, p1));
    u.h[1] = __float22bfloat162_rn(make_float2(p2, p3));
    return u.v;
}

static __device__ __forceinline__ f32x4 mfma16x32(s16x8 a, s16x8 b, f32x4 c) {
    return __builtin_amdgcn_mfma_f32_16x16x32_bf16(a, b, c, 0, 0, 0);
}
static __device__ __forceinline__ f32x4 mfma16x16(s16x4 a, s16x4 b, f32x4 c) {
#if __has_builtin(__builtin_amdgcn_mfma_f32_16x16x16bf16_1k)
    return __builtin_amdgcn_mfma_f32_16x16x16bf16_1k(a, b, c, 0, 0, 0);
#else
    asm volatile("v_mfma_f32_16x16x16_bf16 %0, %1, %2, %0" : "+v"(c) : "v"(a), "v"(b));
    return c;
#endif
}
// async global->LDS, 16B per lane; LDS dest must be linear in lane order.
static __device__ __forceinline__ void gload_lds16(const void* g, void* l) {
    __builtin_amdgcn_global_load_lds(
        (const __attribute__((address_space(1))) unsigned int*)g,
        (__attribute__((address_space(3))) unsigned int*)l, 16, 0, 0);
}

// ---------------------------------------------------------------------------
// fp32 -> bf16 convert for x, W_qkv, W_proj
// ---------------------------------------------------------------------------
__global__ __launch_bounds__(256)
void cvt3_kernel(const float* __restrict__ s0, u16* __restrict__ d0, int n0,
                 const float* __restrict__ s1, u16* __restrict__ d1, int n1,
                 const float* __restrict__ s2, u16* __restrict__ d2, int n2)
{
    const int idx4 = (blockIdx.x * 256 + threadIdx.x) * 4;
    const float* s; u16* d; int local;
    if (idx4 < n0)           { s = s0; d = d0; local = idx4; }
    else if (idx4 < n0 + n1) { s = s1; d = d1; local = idx4 - n0; }
    else if (idx4 < n0 + n1 + n2) { s = s2; d = d2; local = idx4 - n0 - n1; }
    else return;
    float4 v = *(const float4*)(s + local);
    ushort4 o;
    o.x = f2bf(v.x); o.y = f2bf(v.y); o.z = f2bf(v.z); o.w = f2bf(v.w);
    *(ushort4*)(d + local) = o;
}

// ---------------------------------------------------------------------------
// bf16 MFMA GEMM (NT): C[M,N] = A[M,K] @ B[N,K]^T + bias[N]
// ---------------------------------------------------------------------------
template<int BM, int BN, int MODE>
__global__ __launch_bounds__(256)
void mfma_gemm_kernel(const u16* __restrict__ A, const u16* __restrict__ Bw,
                      const float* __restrict__ bias,
                      float* __restrict__ outf,
                      u16* __restrict__ qo, u16* __restrict__ ko, u16* __restrict__ vt,
                      int M, int N, int K)
{
    constexpr int BK = 32;
    __shared__ u16 As[BM * BK];
    __shared__ u16 Bs[BN * BK];
    const int tid = threadIdx.x;
    const int wave = tid >> 6, lane = tid & 63;
    const int wr = wave >> 1, wc = wave & 1;
    constexpr int WM = BM / 2, WN = BN / 2, FI = WM / 16, FJ = WN / 16;
    const int g = lane >> 4, c = lane & 15;
    const int bm = blockIdx.x * BM, bn = blockIdx.y * BN;

    f32x4 acc[FI][FJ] = {};

    constexpr int IA = (BM * BK * 2) / (256 * 16);
    constexpr int IB = (BN * BK * 2) / (256 * 16);

    const u16* asrc[IA]; const u16* bsrc[IB];
    #pragma unroll
    for (int i = 0; i < IA; ++i) {
        const int idx = tid + i * 256;
        const int row = idx >> 2, kc = idx & 3;
        const int kcs = kc ^ ((row >> 1) & 3);
        asrc[i] = A + (size_t)(bm + row) * K + kcs * 8;
    }
    #pragma unroll
    for (int i = 0; i < IB; ++i) {
        const int idx = tid + i * 256;
        const int row = idx >> 2, kc = idx & 3;
        const int kcs = kc ^ ((row >> 1) & 3);
        bsrc[i] = Bw + (size_t)(bn + row) * K + kcs * 8;
    }
    const int gsw = g ^ ((c >> 1) & 3);

    for (int k0 = 0; k0 < K; k0 += BK) {
        if (k0) __syncthreads();
        #pragma unroll
        for (int i = 0; i < IA; ++i) gload_lds16(asrc[i] + k0, &As[(tid + i * 256) * 8]);
        #pragma unroll
        for (int i = 0; i < IB; ++i) gload_lds16(bsrc[i] + k0, &Bs[(tid + i * 256) * 8]);
        __syncthreads();

        s16x8 af[FI], bfr[FJ];
        #pragma unroll
        for (int i = 0; i < FI; ++i)
            af[i] = *(const s16x8*)&As[(wr * WM + i * 16 + c) * BK + gsw * 8];
        #pragma unroll
        for (int j = 0; j < FJ; ++j)
            bfr[j] = *(const s16x8*)&Bs[(wc * WN + j * 16 + c) * BK + gsw * 8];
        #pragma unroll
        for (int i = 0; i < FI; ++i)
            #pragma unroll
            for (int j = 0; j < FJ; ++j)
                acc[i][j] = mfma16x32(af[i], bfr[j], acc[i][j]);
    }

    if (MODE == 1) {
        #pragma unroll
        for (int j = 0; j < FJ; ++j) {
            const int col = bn + wc * WN + j * 16 + c;
            const float bv = bias[col];
            #pragma unroll
            for (int i = 0; i < FI; ++i) {
                const int row0 = bm + wr * WM + i * 16 + g * 4;
                #pragma unroll
                for (int r = 0; r < 4; ++r)
                    outf[(size_t)(row0 + r) * N + col] = acc[i][j][r] + bv;
            }
        }
    } else {
        const int which = bn / D_MODEL;
        #pragma unroll
        for (int j = 0; j < FJ; ++j) {
            const int gcol = bn + wc * WN + j * 16 + c;
            const float bv = bias[gcol];
            const int scol = gcol - which * D_MODEL;
            const int h = scol >> 6, d = scol & 63;
            if (which == 2) {
                #pragma unroll
                for (int i = 0; i < FI; ++i) {
                    const int row0 = bm + wr * WM + i * 16 + g * 4;
                    const int b = row0 >> 11, t = row0 & 2047;
                    ushort4 pv;
                    pv.x = f2bf(acc[i][j][0] + bv);
                    pv.y = f2bf(acc[i][j][1] + bv);
                    pv.z = f2bf(acc[i][j][2] + bv);
                    pv.w = f2bf(acc[i][j][3] + bv);
                    *(ushort4*)(vt + ((size_t)(b * N_HEADS + h) * 64 + d) * SEQ + t) = pv;
                }
            } else {
                u16* dst = (which == 0) ? qo : ko;
                const float sc = (which == 0) ? SCALE_Q : 1.0f;  // q in log2-domain units
                #pragma unroll
                for (int i = 0; i < FI; ++i) {
                    const int row0 = bm + wr * WM + i * 16 + g * 4;
                    const int b = row0 >> 11, t = row0 & 2047;
                    #pragma unroll
                    for (int r = 0; r < 4; ++r)
                        dst[(((size_t)(b * N_HEADS + h) * SEQ + t + r) << 6) + d] =
                            f2bf((acc[i][j][r] + bv) * sc);
                }
            }
        }
    }
}

// ---------------------------------------------------------------------------
// MFMA flash attention — FINAL (r13 config, best-known: attn 50.7us, total
// 96.5us; VGPR 84 / unified 148, no spills). 64 q-rows per wave (4 x 16-q
// subtiles share each K/V load), 4-way in-block kv split, depth-1 register
// prefetch ring, in-LDS 4-slice combine, direct bf16 ao write.
// __launch_bounds__(256,3): 3 waves/SIMD -> 3 blocks/CU = the 768-block grid
// exactly co-resident. Residual imbalance (heaviest block 32 iters vs mean
// 16.5) is structural: five schemes to cap the span (heavy-split r14,
// pair-phase r15/r18, setprio r16, depth-3 ring r17) all regressed via
// residency overflow or register-cap spills. This is the banked optimum.
// ---------------------------------------------------------------------------
__global__ __launch_bounds__(256, 3)
void mfma_attn_kernel(const u16* __restrict__ qb, const u16* __restrict__ kb,
                      const u16* __restrict__ vtb, u16* __restrict__ ob)
{
    __shared__ __align__(16) u16 OL[NSL][64][64];     // 32 KB
    __shared__ float ML[NSL][2][64];                  // 2 KB
    const int tid = threadIdx.x;
    const int lane = tid & 63;
    const int s = tid >> 6;                          // kv-slice = wave id (0..3)
    const int blk = blockIdx.x;
    const int bh = blk % NBH;
    const int q = blk / NBH;                         // 0..31
    // round-robin-aware balance map (CU sums ~const; last 256 blocks lightest)
    const int jblk = (q <= 10) ? (q + 21) : (q <= 20) ? (31 - q) : (q - 21);

    const int nq = jblk + 1;                         // tiles per slice (exact)
    const int t0 = s * nq;
    const int t1 = t0 + nq;
    const int jq0 = 4 * jblk;                        // kv-tile index of q-subtile 0

    const int g = lane >> 4, c = lane & 15;
    const int rbase = g << 2;
    const int q0 = jblk << 6;

    // Q fragments for 4 subtiles
    s16x8 qa0[4], qa1[4];
    #pragma unroll
    for (int qq = 0; qq < 4; ++qq) {
        const u16* qp = qb + ((size_t)bh * SEQ + q0 + qq * 16 + c) * 64 + g * 8;
        qa0[qq] = *(const s16x8*)(qp);
        qa1[qq] = *(const s16x8*)(qp + 32);
    }

    f32x4 o[4][4] = {};
    float m[4] = {0.f, 0.f, 0.f, 0.f};
    float l[4] = {0.f, 0.f, 0.f, 0.f};

#define TILEQ(QQ, CK0, CK1, CV0, CV1, CV2, CV3, MASKED) {                         \
    f32x4 sa = {0,0,0,0}, sb = {0,0,0,0};                                         \
    sa = mfma16x32(CK0, qa0[QQ], sa);                                             \
    sb = mfma16x32(CK1, qa1[QQ], sb);                                             \
    f32x4 sv = sa + sb;                                                           \
    if (MASKED) {                                                                 \
        if (rbase + 0 > c) sv[0] = -1e30f;                                        \
        if (rbase + 1 > c) sv[1] = -1e30f;                                        \
        if (rbase + 2 > c) sv[2] = -1e30f;                                        \
        if (rbase + 3 > c) sv[3] = -1e30f;                                        \
    }                                                                             \
    float pmax = fmaxf(fmaxf(sv[0], sv[1]), fmaxf(sv[2], sv[3]));                 \
    if (__any(pmax > m[QQ] + 8.f)) {           /* rare: full rescale */           \
        pmax = fmaxf(pmax, __shfl_xor(pmax, 16));                                 \
        pmax = fmaxf(pmax, __shfl_xor(pmax, 32));                                 \
        const float mn = fmaxf(m[QQ], pmax);                                      \
        const float scr = e2(m[QQ] - mn);                                         \
        l[QQ] *= scr;                                                             \
        f32x4 scv;                                                                \
        scv[0] = __shfl(scr, rbase + 0);                                          \
        scv[1] = __shfl(scr, rbase + 1);                                          \
        scv[2] = __shfl(scr, rbase + 2);                                          \
        scv[3] = __shfl(scr, rbase + 3);                                          \
        o[QQ][0] *= scv; o[QQ][1] *= scv; o[QQ][2] *= scv; o[QQ][3] *= scv;       \
        m[QQ] = mn;                                                               \
    }                                                                             \
    const float p0 = e2(sv[0] - m[QQ]), p1 = e2(sv[1] - m[QQ]);                   \
    const float p2 = e2(sv[2] - m[QQ]), p3 = e2(sv[3] - m[QQ]);                   \
    l[QQ] += (p0 + p1) + (p2 + p3);                                               \
    const s16x4 pa = pk4(p0, p1, p2, p3);                                         \
    o[QQ][0] = mfma16x16(pa, CV0, o[QQ][0]);                                      \
    o[QQ][1] = mfma16x16(pa, CV1, o[QQ][1]);                                      \
    o[QQ][2] = mfma16x16(pa, CV2, o[QQ][2]);                                      \
    o[QQ][3] = mfma16x16(pa, CV3, o[QQ][3]);                                      \
}

    {
        const u16* kp = kb + (size_t)bh * SEQ * 64 + c * 64 + g * 8 + (size_t)t0 * 1024;
        const u16* vp = vtb + ((size_t)bh * 64 + c) * SEQ + g * 4 + t0 * 16;

        // preload tile t0
        s16x8 ck0 = *(const s16x8*)(kp);
        s16x8 ck1 = *(const s16x8*)(kp + 32);
        s16x4 cv0 = *(const s16x4*)(vp);
        s16x4 cv1 = *(const s16x4*)(vp + 16 * SEQ);
        s16x4 cv2 = *(const s16x4*)(vp + 32 * SEQ);
        s16x4 cv3 = *(const s16x4*)(vp + 48 * SEQ);

        for (int t = t0; t < t1; ++t) {
            // prefetch tile t+1 (unconditional; stays inside ws buffers)
            kp += 1024; vp += 16;
            const s16x8 nk0 = *(const s16x8*)(kp);
            const s16x8 nk1 = *(const s16x8*)(kp + 32);
            const s16x4 nv0 = *(const s16x4*)(vp);
            const s16x4 nv1 = *(const s16x4*)(vp + 16 * SEQ);
            const s16x4 nv2 = *(const s16x4*)(vp + 32 * SEQ);
            const s16x4 nv3 = *(const s16x4*)(vp + 48 * SEQ);

            #pragma unroll
            for (int qq = 0; qq < 4; ++qq) {
                if (t <= jq0 + qq) {                 // wave-uniform causal skip
                    TILEQ(qq, ck0, ck1, cv0, cv1, cv2, cv3, (t == jq0 + qq));
                }
            }
            ck0 = nk0; ck1 = nk1;
            cv0 = nv0; cv1 = nv1; cv2 = nv2; cv3 = nv3;
        }
    }
#undef TILEQ

    // ---- store partial to LDS (chunk-XOR swizzle: chunk' = chunk ^ (row&7)) --
    u16* OLs = &OL[s][0][0];
    #pragma unroll
    for (int qq = 0; qq < 4; ++qq) {
        float lt = l[qq] + __shfl_xor(l[qq], 16);
        lt += __shfl_xor(lt, 32);
        #pragma unroll
        for (int r = 0; r < 4; ++r) {
            const int row = qq * 16 + rbase + r;
            #pragma unroll
            for (int j = 0; j < 4; ++j) {
                const int col = c + 16 * j;
                const int idx = row * 64 + ((((col >> 3) ^ (row & 7)) << 3) | (col & 7));
                OLs[idx] = f2bf(o[qq][j][r]);
            }
        }
        if (g == 0) {
            ML[s][0][qq * 16 + c] = m[qq];
            ML[s][1][qq * 16 + c] = lt;
        }
    }
    __syncthreads();

    // ---- in-block combine: 256 threads, each does one (row, 16-col quarter) --
    {
        const int row = tid >> 2;                    // 0..63
        const int cq = (tid & 3) << 4;               // 0,16,32,48
        float mv[NSL], lv[NSL];
        float mm = -3.0e38f;
        #pragma unroll
        for (int sp = 0; sp < NSL; ++sp) {
            mv[sp] = ML[sp][0][row];
            lv[sp] = ML[sp][1][row];
            mm = fmaxf(mm, mv[sp]);
        }
        float w[NSL], denom = 0.f;
        #pragma unroll
        for (int sp = 0; sp < NSL; ++sp) {
            w[sp] = e2(mv[sp] - mm);                 // empty (row,slice): l=0 -> no-op
            denom += lv[sp] * w[sp];
        }
        const float inv = 1.0f / denom;              // diagonal slice always > 0

        float a[16] = {};
        #pragma unroll
        for (int sp = 0; sp < NSL; ++sp) {
            const float ws = w[sp] * inv;
            #pragma unroll
            for (int h2 = 0; h2 < 2; ++h2) {
                const int ch = (cq >> 3) + h2;
                const int idx = row * 64 + ((ch ^ (row & 7)) << 3);
                const uint4 xv = *(const uint4*)&OL[sp][0][idx];
                a[h2 * 8 + 0] += ws * b2f((u16)(xv.x & 0xffff));
                a[h2 * 8 + 1] += ws * b2f((u16)(xv.x >> 16));
                a[h2 * 8 + 2] += ws * b2f((u16)(xv.y & 0xffff));
                a[h2 * 8 + 3] += ws * b2f((u16)(xv.y >> 16));
                a[h2 * 8 + 4] += ws * b2f((u16)(xv.z & 0xffff));
                a[h2 * 8 + 5] += ws * b2f((u16)(xv.z >> 16));
                a[h2 * 8 + 6] += ws * b2f((u16)(xv.w & 0xffff));
                a[h2 * 8 + 7] += ws * b2f((u16)(xv.w >> 16));
            }
        }

        const int b = bh / N_HEADS, h = bh % N_HEADS;
        const int t = (jblk << 6) + row;
        u16* dst = ob + ((size_t)b * SEQ + t) * D_MODEL + h * 64 + cq;
        #pragma unroll
        for (int e4 = 0; e4 < 4; ++e4) {
            ushort4 ov;
            ov.x = f2bf(a[e4 * 4 + 0]);
            ov.y = f2bf(a[e4 * 4 + 1]);
            ov.z = f2bf(a[e4 * 4 + 2]);
            ov.w = f2bf(a[e4 * 4 + 3]);
            *(ushort4*)(dst + e4 * 4) = ov;
        }
    }
}

// ---------------------------------------------------------------------------
extern "C" void kernel_launch(void* const* d_in, const int* in_sizes, int n_in,
                              void* d_out, int out_size, void* d_ws, size_t ws_size,
                              hipStream_t stream)
{
    const float* x      = (const float*)d_in[0];
    // d_in[1] = mask: exactly triu(k=1) causal; applied analytically in-kernel.
    const float* W_qkv  = (const float*)d_in[2];
    const float* b_qkv  = (const float*)d_in[3];
    const float* W_proj = (const float*)d_in[4];
    const float* b_proj = (const float*)d_in[5];
    float* out = (float*)d_out;

    const int nX = BATCH * SEQ * D_MODEL;
    const int nWq = 3 * D_MODEL * D_MODEL;
    const int nWp = D_MODEL * D_MODEL;
    u16* xb  = (u16*)d_ws;
    u16* wqb = xb + nX;
    u16* wpb = wqb + nWq;
    u16* qbf = wpb + nWp;
    u16* kbf = qbf + nX;
    u16* vtb = kbf + nX;
    u16* ao  = vtb + nX;                 // bf16 [B,T,C]

    const int tot4 = (nX + nWq + nWp) / 4;
    cvt3_kernel<<<(tot4 + 255) / 256, 256, 0, stream>>>(x, xb, nX, W_qkv, wqb, nWq,
                                                        W_proj, wpb, nWp);

    mfma_gemm_kernel<128, 128, 0><<<dim3(32, 18), 256, 0, stream>>>(
        xb, wqb, b_qkv, nullptr, qbf, kbf, vtb, BATCH * SEQ, 3 * D_MODEL, D_MODEL);

    // 64 q-rows/wave, 4-way in-block split-K, 3 blocks/CU co-resident
    mfma_attn_kernel<<<dim3(NQ64 * NBH), 256, 0, stream>>>(
        qbf, kbf, vtb, ao);

    mfma_gemm_kernel<128, 64, 1><<<dim3(32, 12), 256, 0, stream>>>(
        ao, wpb, b_proj, out, nullptr, nullptr, nullptr, BATCH * SEQ, D_MODEL, D_MODEL);
}